// Round 4
// baseline (2388.509 us; speedup 1.0000x reference)
//
#include <hip/hip_runtime.h>

#define NN 50000
#define F_IN 17
#define HIDC 64
#define NLAYERS 12
#define NE 400000
#define NET (NE + NN)
#define EPS_BN 1e-5f

typedef unsigned short u16;
typedef __bf16 bf16x8 __attribute__((ext_vector_type(8)));
typedef float f32x4 __attribute__((ext_vector_type(4)));

__device__ __forceinline__ float bf2f(u16 v) {
    union { unsigned int i; float f; } u; u.i = ((unsigned int)v) << 16; return u.f;
}
__device__ __forceinline__ u16 f2bf(float f) {
    union { float f; unsigned int i; } u; u.f = f;
    unsigned int r = u.i + 0x7fffu + ((u.i >> 16) & 1u);
    return (u16)(r >> 16);
}

__global__ void k_zero_i(int* __restrict__ p, int n) {
    int i = blockIdx.x * blockDim.x + threadIdx.x;
    if (i < n) p[i] = 0;
}
__global__ void k_zero_f(float* __restrict__ p, int n) {
    int i = blockIdx.x * blockDim.x + threadIdx.x;
    if (i < n) p[i] = 0.f;
}

// ---- transposed split-bf16 concat weights: WT[i][j][k] = (j<128?Wl:Wr)[i][k][j'] ----
__global__ void k_wt(const float* __restrict__ Wl, const float* __restrict__ Wr,
                     u16* __restrict__ WThi, u16* __restrict__ WTlo) {
    int t = blockIdx.x * blockDim.x + threadIdx.x;
    if (t >= NLAYERS * 256 * HIDC) return;
    int k = t & 63, j = (t >> 6) & 255, i = t >> 14;
    int jj = (j < 128) ? j : (j - 128);
    float v = (j < 128) ? Wl[(i * HIDC + k) * 128 + jj] : Wr[(i * HIDC + k) * 128 + jj];
    u16 hi = f2bf(v);
    u16 lo = f2bf(v - bf2f(hi));
    WThi[t] = hi; WTlo[t] = lo;
}

// ---- CSR build ----
__global__ void k_count(const int* __restrict__ ei, int* __restrict__ deg) {
    int e = blockIdx.x * blockDim.x + threadIdx.x;
    if (e < NE) {
        int d = ei[NE + e];
        if ((unsigned)d < NN) atomicAdd(&deg[d], 1);
    }
}

__global__ void k_scan(const int* __restrict__ deg, int* __restrict__ rp, int* __restrict__ cur) {
    __shared__ int sums[1024];
    int t = threadIdx.x;
    const int CH = (NN + 1023) / 1024;
    int base = t * CH, s = 0;
    for (int i = 0; i < CH; i++) { int n = base + i; if (n < NN) s += deg[n] + 1; }
    sums[t] = s; __syncthreads();
    for (int off = 1; off < 1024; off <<= 1) {
        int v = sums[t];
        int w = (t >= off) ? sums[t - off] : 0;
        __syncthreads();
        sums[t] = v + w;
        __syncthreads();
    }
    int run = (t == 0) ? 0 : sums[t - 1];
    for (int i = 0; i < CH; i++) {
        int n = base + i;
        if (n < NN) { rp[n] = run; cur[n] = run; run += deg[n] + 1; }
    }
    if (t == 1023) rp[NN] = sums[1023];
}

__global__ void k_scatter(const int* __restrict__ ei, int* __restrict__ cur, int* __restrict__ col) {
    int e = blockIdx.x * blockDim.x + threadIdx.x;
    if (e >= NET) return;
    int s, d;
    if (e < NE) { s = ei[e]; d = ei[NE + e]; } else { s = d = e - NE; }
    if ((unsigned)s >= NN) s = 0;
    if ((unsigned)d >= NN) d = 0;
    int p = atomicAdd(&cur[d], 1);
    if ((unsigned)p < NET) col[p] = s;
}

// ---- input projection + BN partial sums ----
__global__ void k_inproj(const float* __restrict__ x, const float* __restrict__ W, const float* __restrict__ b,
                         float* __restrict__ g, float* __restrict__ bns) {
    __shared__ float ls[64], lq[64];
    int t = threadIdx.x;
    if (t < 64) { ls[t] = 0.f; lq[t] = 0.f; }
    __syncthreads();
    int j = t & 63;
    float wcol[F_IN];
#pragma unroll
    for (int k = 0; k < F_IN; k++) wcol[k] = W[k * 64 + j];
    float bias = b[j];
    float sA = 0.f, sQ = 0.f;
    for (int idx = blockIdx.x * blockDim.x + t; idx < NN * 64; idx += gridDim.x * blockDim.x) {
        int node = idx >> 6;
        float acc = bias;
#pragma unroll
        for (int k = 0; k < F_IN; k++) acc += x[node * F_IN + k] * wcol[k];
        g[idx] = acc;
        sA += acc; sQ += acc * acc;
    }
    atomicAdd(&ls[j], sA); atomicAdd(&lq[j], sQ);
    __syncthreads();
    if (t < 64) atomicAdd(&bns[t], ls[t]);
    else if (t < 128) atomicAdd(&bns[t], lq[t - 64]);
}

// ---- BN finalize + ELU (+residual), update h f32 and split-bf16 hi/lo ----
__global__ void k_bnapply(const float* __restrict__ g, const float* __restrict__ bns,
                          const float* __restrict__ gamma, const float* __restrict__ beta,
                          float* h, u16* __restrict__ hbhi, u16* __restrict__ hblo, int residual) {
    int t = blockIdx.x * blockDim.x + threadIdx.x;
    if (t >= NN * 16) return;
    int c4 = (t & 15) * 4;
    float4 gg = *(const float4*)(g + (size_t)t * 4);
    float4 out;
#pragma unroll
    for (int r = 0; r < 4; r++) {
        int c = c4 + r;
        float mean = bns[c] * (1.0f / NN);
        float var = bns[64 + c] * (1.0f / NN) - mean * mean;
        var = fmaxf(var, 0.f);
        float rstd = rsqrtf(var + EPS_BN);
        float v = ((&gg.x)[r] - mean) * rstd * gamma[c] + beta[c];
        (&out.x)[r] = v > 0.f ? v : (__expf(v) - 1.f);
    }
    if (residual) {
        float4 hh = *(const float4*)(h + (size_t)t * 4);
        out.x += hh.x; out.y += hh.y; out.z += hh.z; out.w += hh.w;
    }
    *(float4*)(h + (size_t)t * 4) = out;
    ushort4 phi, plo;
#pragma unroll
    for (int r = 0; r < 4; r++) {
        float v = (&out.x)[r];
        u16 hi = f2bf(v);
        u16 lo = f2bf(v - bf2f(hi));
        (&phi.x)[r] = hi; (&plo.x)[r] = lo;
    }
    *(ushort4*)(hbhi + (size_t)t * 4) = phi;
    *(ushort4*)(hblo + (size_t)t * 4) = plo;
}

// ---- xl|xr GEMM via MFMA, split-bf16 A and B (drop lo*lo) ≈ f32 exact ----
__global__ __launch_bounds__(256) void k_gemm(const u16* __restrict__ hbhi, const u16* __restrict__ hblo,
                                              const u16* __restrict__ WThi, const u16* __restrict__ WTlo,
                                              float* __restrict__ xlxr) {
    int lane = threadIdx.x & 63;
    int wv = threadIdx.x >> 6;
    int node0 = blockIdx.x * 16;
    int col0 = (blockIdx.y * 4 + wv) * 16;
    int ml = lane & 15;
    int kb = (lane >> 4) * 8;
    size_t arow = (size_t)(node0 + ml) * 64 + kb;
    size_t brow = (size_t)(col0 + ml) * 64 + kb;
    bf16x8 ah0 = *(const bf16x8*)(hbhi + arow);
    bf16x8 ah1 = *(const bf16x8*)(hbhi + arow + 32);
    bf16x8 al0 = *(const bf16x8*)(hblo + arow);
    bf16x8 al1 = *(const bf16x8*)(hblo + arow + 32);
    bf16x8 bh0 = *(const bf16x8*)(WThi + brow);
    bf16x8 bh1 = *(const bf16x8*)(WThi + brow + 32);
    bf16x8 bl0 = *(const bf16x8*)(WTlo + brow);
    bf16x8 bl1 = *(const bf16x8*)(WTlo + brow + 32);
    f32x4 acc = {0.f, 0.f, 0.f, 0.f};
    acc = __builtin_amdgcn_mfma_f32_16x16x32_bf16(al0, bh0, acc, 0, 0, 0);
    acc = __builtin_amdgcn_mfma_f32_16x16x32_bf16(al1, bh1, acc, 0, 0, 0);
    acc = __builtin_amdgcn_mfma_f32_16x16x32_bf16(ah0, bl0, acc, 0, 0, 0);
    acc = __builtin_amdgcn_mfma_f32_16x16x32_bf16(ah1, bl1, acc, 0, 0, 0);
    acc = __builtin_amdgcn_mfma_f32_16x16x32_bf16(ah0, bh0, acc, 0, 0, 0);
    acc = __builtin_amdgcn_mfma_f32_16x16x32_bf16(ah1, bh1, acc, 0, 0, 0);
    int colj = col0 + ml;
    int row = node0 + (lane >> 4) * 4;
#pragma unroll
    for (int r = 0; r < 4; r++) xlxr[(size_t)(row + r) * 256 + colj] = acc[r];
}

// ---- GATv2 attention: wave per dst, online softmax, + BN partial sums ----
__global__ __launch_bounds__(256) void k_edge(const float* __restrict__ xlxr, const int* __restrict__ rp,
                                              const int* __restrict__ col, const float* __restrict__ attL,
                                              const float* __restrict__ cbL, float* __restrict__ g,
                                              float* __restrict__ bns) {
    __shared__ float ls[64], lq[64];
    int t = threadIdx.x;
    if (t < 64) { ls[t] = 0.f; lq[t] = 0.f; }
    __syncthreads();
    int lane = t & 63;
    int wid = blockIdx.x * 4 + (t >> 6);
    int nw = gridDim.x * 4;
    float at0 = attL[2 * lane];
    float at1 = attL[2 * lane + 1];
    float cb0 = 0.f, cb1 = 0.f;
    if (lane < 32) { cb0 = cbL[2 * lane]; cb1 = cbL[2 * lane + 1]; }
    float s0acc = 0.f, s1acc = 0.f, q0acc = 0.f, q1acc = 0.f;
    for (int d = wid; d < NN; d += nw) {
        float2 xr2 = *(const float2*)(xlxr + (size_t)d * 256 + 128 + 2 * lane);
        int beg = rp[d], end = rp[d + 1];
        int s = col[beg];
        if ((unsigned)s >= NN) s = 0;
        float2 xl = *(const float2*)(xlxr + (size_t)s * 256 + 2 * lane);
        float m = -1e30f, lsum = 0.f, a0c = 0.f, a1c = 0.f;
        for (int q = beg; q < end; q++) {
            float a0 = xl.x, a1 = xl.y;
            if (q + 1 < end) {
                int s2 = col[q + 1];
                if ((unsigned)s2 >= NN) s2 = 0;
                xl = *(const float2*)(xlxr + (size_t)s2 * 256 + 2 * lane);
            }
            float u0 = a0 + xr2.x, u1 = a1 + xr2.y;
            float l0 = u0 > 0.f ? u0 : 0.2f * u0;
            float l1 = u1 > 0.f ? u1 : 0.2f * u1;
            float e = l0 * at0 + l1 * at1;
            e += __shfl_xor(e, 1); e += __shfl_xor(e, 2); e += __shfl_xor(e, 4);
            e += __shfl_xor(e, 8); e += __shfl_xor(e, 16);
            float mn = fmaxf(m, e);
            float sc = __expf(m - mn);
            float pw = __expf(e - mn);
            lsum = lsum * sc + pw;
            a0c = a0c * sc + pw * a0;
            a1c = a1c * sc + pw * a1;
            m = mn;
        }
        float inv = 1.0f / (lsum + 1e-16f);
        float v0 = a0c * inv, v1 = a1c * inv;
        float w0 = 0.5f * (v0 + __shfl_xor(v0, 32));
        float w1 = 0.5f * (v1 + __shfl_xor(v1, 32));
        if (lane < 32) {
            float c0 = w0 + cb0, c1 = w1 + cb1;
            float2 o; o.x = c0; o.y = c1;
            *(float2*)(g + (size_t)d * 64 + 2 * lane) = o;
            s0acc += c0; q0acc += c0 * c0;
            s1acc += c1; q1acc += c1 * c1;
        }
    }
    if (lane < 32) {
        atomicAdd(&ls[2 * lane], s0acc); atomicAdd(&ls[2 * lane + 1], s1acc);
        atomicAdd(&lq[2 * lane], q0acc); atomicAdd(&lq[2 * lane + 1], q1acc);
    }
    __syncthreads();
    if (t < 64) atomicAdd(&bns[t], ls[t]);
    else if (t < 128) atomicAdd(&bns[t], lq[t - 64]);
}

// ---- output head: half-wave per node, fused MLP + sigmoid, f32 out ----
__global__ void k_head(const float* __restrict__ h, const float* __restrict__ W1, const float* __restrict__ b1,
                       const float* __restrict__ W2, const float* __restrict__ b2, float* __restrict__ out) {
    int t = blockIdx.x * blockDim.x + threadIdx.x;
    int node = t >> 5;
    int j = t & 31;
    if (node >= NN) return;
    float acc = b1[j];
    const float* hr = h + (size_t)node * 64;
#pragma unroll
    for (int k = 0; k < 64; k++) acc += hr[k] * W1[k * 32 + j];
    float e = acc > 0.f ? acc : (__expf(acc) - 1.f);
    float z = e * W2[j];
    z += __shfl_xor(z, 1); z += __shfl_xor(z, 2); z += __shfl_xor(z, 4);
    z += __shfl_xor(z, 8); z += __shfl_xor(z, 16);
    if (j == 0) {
        float y = z + b2[0];
        out[node] = 1.0f / (1.0f + __expf(-y));
    }
}

extern "C" void kernel_launch(void* const* d_in, const int* in_sizes, int n_in,
                              void* d_out, int out_size, void* d_ws, size_t ws_size,
                              hipStream_t stream) {
    const float* x = (const float*)d_in[0];
    const int* ei = (const int*)d_in[1];
    const float* inW = (const float*)d_in[2];
    const float* inb = (const float*)d_in[3];
    const float* ing = (const float*)d_in[4];
    const float* inbeta = (const float*)d_in[5];
    const float* Wl = (const float*)d_in[6];
    const float* Wr = (const float*)d_in[7];
    const float* att = (const float*)d_in[8];
    const float* cb = (const float*)d_in[9];
    const float* bng = (const float*)d_in[10];
    const float* bnb = (const float*)d_in[11];
    const float* W1 = (const float*)d_in[12];
    const float* b1 = (const float*)d_in[13];
    const float* W2 = (const float*)d_in[14];
    const float* b2 = (const float*)d_in[15];
    float* out = (float*)d_out;  // reference output dtype is float32

    char* ws = (char*)d_ws;
    size_t off = 0;
    auto alloc = [&](size_t bytes) -> char* {
        char* p = ws + off;
        off = (off + bytes + 255) & ~(size_t)255;
        return p;
    };
    float* h    = (float*)alloc((size_t)NN * 64 * 4);
    float* g    = (float*)alloc((size_t)NN * 64 * 4);
    float* xlxr = (float*)alloc((size_t)NN * 256 * 4);
    u16* hbhi   = (u16*)alloc((size_t)NN * 64 * 2);
    u16* hblo   = (u16*)alloc((size_t)NN * 64 * 2);
    u16* WThi   = (u16*)alloc((size_t)NLAYERS * 256 * 64 * 2);
    u16* WTlo   = (u16*)alloc((size_t)NLAYERS * 256 * 64 * 2);
    int* deg    = (int*)alloc((size_t)NN * 4);
    int* rp     = (int*)alloc((size_t)(NN + 1) * 4);
    int* cur    = (int*)alloc((size_t)NN * 4);
    int* colv   = (int*)alloc((size_t)NET * 4);
    float* bns  = (float*)alloc((size_t)(NLAYERS + 1) * 128 * 4);

    k_zero_i<<<(NN + 255) / 256, 256, 0, stream>>>(deg, NN);
    k_zero_f<<<((NLAYERS + 1) * 128 + 255) / 256, 256, 0, stream>>>(bns, (NLAYERS + 1) * 128);

    k_wt<<<(NLAYERS * 256 * HIDC + 255) / 256, 256, 0, stream>>>(Wl, Wr, WThi, WTlo);
    k_count<<<(NE + 255) / 256, 256, 0, stream>>>(ei, deg);
    k_scan<<<1, 1024, 0, stream>>>(deg, rp, cur);
    k_scatter<<<(NET + 255) / 256, 256, 0, stream>>>(ei, cur, colv);

    k_inproj<<<512, 256, 0, stream>>>(x, inW, inb, g, bns);
    k_bnapply<<<3125, 256, 0, stream>>>(g, bns, ing, inbeta, h, hbhi, hblo, 0);

    for (int i = 0; i < NLAYERS; i++) {
        k_gemm<<<dim3(3125, 4), 256, 0, stream>>>(hbhi, hblo, WThi + (size_t)i * 16384,
                                                  WTlo + (size_t)i * 16384, xlxr);
        k_edge<<<1024, 256, 0, stream>>>(xlxr, rp, colv, att + (size_t)i * 128, cb + (size_t)i * 64,
                                         g, bns + (size_t)(i + 1) * 128);
        k_bnapply<<<3125, 256, 0, stream>>>(g, bns + (size_t)(i + 1) * 128, bng + (size_t)i * 64,
                                            bnb + (size_t)i * 64, h, hbhi, hblo, 1);
    }
    k_head<<<6250, 256, 0, stream>>>(h, W1, b1, W2, b2, out);
}

// Round 5
// 2030.774 us; speedup vs baseline: 1.1762x; 1.1762x over previous
//
#include <hip/hip_runtime.h>

#define NN 50000
#define F_IN 17
#define HIDC 64
#define NLAYERS 12
#define NE 400000
#define NET (NE + NN)
#define EPS_BN 1e-5f

typedef unsigned short u16;
typedef __bf16 bf16x8 __attribute__((ext_vector_type(8)));
typedef float f32x4 __attribute__((ext_vector_type(4)));

__device__ __forceinline__ float bf2f(u16 v) {
    union { unsigned int i; float f; } u; u.i = ((unsigned int)v) << 16; return u.f;
}
__device__ __forceinline__ u16 f2bf(float f) {
    union { float f; unsigned int i; } u; u.f = f;
    unsigned int r = u.i + 0x7fffu + ((u.i >> 16) & 1u);
    return (u16)(r >> 16);
}
// unpack 2 packed bf16 (low u16 = even channel) to floats
__device__ __forceinline__ float2 bf2x(unsigned int w) {
    union { unsigned int i; float f; } a, b;
    a.i = w << 16; b.i = w & 0xffff0000u;
    float2 r; r.x = a.f; r.y = b.f; return r;
}

__global__ void k_zero_i(int* __restrict__ p, int n) {
    int i = blockIdx.x * blockDim.x + threadIdx.x;
    if (i < n) p[i] = 0;
}
__global__ void k_zero_f(float* __restrict__ p, int n) {
    int i = blockIdx.x * blockDim.x + threadIdx.x;
    if (i < n) p[i] = 0.f;
}

// ---- transposed split-bf16 concat weights: WT[i][j][k] = (j<128?Wl:Wr)[i][k][j'] ----
__global__ void k_wt(const float* __restrict__ Wl, const float* __restrict__ Wr,
                     u16* __restrict__ WThi, u16* __restrict__ WTlo) {
    int t = blockIdx.x * blockDim.x + threadIdx.x;
    if (t >= NLAYERS * 256 * HIDC) return;
    int k = t & 63, j = (t >> 6) & 255, i = t >> 14;
    int jj = (j < 128) ? j : (j - 128);
    float v = (j < 128) ? Wl[(i * HIDC + k) * 128 + jj] : Wr[(i * HIDC + k) * 128 + jj];
    u16 hi = f2bf(v);
    u16 lo = f2bf(v - bf2f(hi));
    WThi[t] = hi; WTlo[t] = lo;
}

// ---- CSR build ----
__global__ void k_count(const int* __restrict__ ei, int* __restrict__ deg) {
    int e = blockIdx.x * blockDim.x + threadIdx.x;
    if (e < NE) {
        int d = ei[NE + e];
        if ((unsigned)d < NN) atomicAdd(&deg[d], 1);
    }
}

// 2-level scan: per-block inclusive scan + block partials
__global__ void k_scan1(const int* __restrict__ deg, int* __restrict__ tmp, int* __restrict__ part) {
    __shared__ int s[256];
    int b = blockIdx.x, t = threadIdx.x;
    int n = b * 256 + t;
    int v = (n < NN) ? deg[n] + 1 : 0;
    s[t] = v; __syncthreads();
    for (int o = 1; o < 256; o <<= 1) {
        int a = s[t];
        int w = (t >= o) ? s[t - o] : 0;
        __syncthreads();
        s[t] = a + w;
        __syncthreads();
    }
    if (n < NN) tmp[n] = s[t];
    if (t == 255) part[b] = s[255];
}
__global__ void k_scan2(int* __restrict__ part) {  // 196 partials -> exclusive, total at [196]
    __shared__ int s[256];
    int t = threadIdx.x;
    int v = (t < 196) ? part[t] : 0;
    s[t] = v; __syncthreads();
    for (int o = 1; o < 256; o <<= 1) {
        int a = s[t];
        int w = (t >= o) ? s[t - o] : 0;
        __syncthreads();
        s[t] = a + w;
        __syncthreads();
    }
    if (t < 196) part[t] = s[t] - v;
    if (t == 195) part[196] = s[195];
}
__global__ void k_scan3(const int* __restrict__ deg, const int* __restrict__ tmp,
                        const int* __restrict__ part, int* __restrict__ rp, int* __restrict__ cur) {
    int b = blockIdx.x, t = threadIdx.x;
    int n = b * 256 + t;
    if (n < NN) {
        int e = tmp[n] - (deg[n] + 1) + part[b];
        rp[n] = e; cur[n] = e;
    }
    if (n == 0) rp[NN] = part[196];
}

__global__ void k_scatter(const int* __restrict__ ei, int* __restrict__ cur, int* __restrict__ col) {
    int e = blockIdx.x * blockDim.x + threadIdx.x;
    if (e >= NET) return;
    int s, d;
    if (e < NE) { s = ei[e]; d = ei[NE + e]; } else { s = d = e - NE; }
    if ((unsigned)s >= NN) s = 0;
    if ((unsigned)d >= NN) d = 0;
    int p = atomicAdd(&cur[d], 1);
    if ((unsigned)p < NET) col[p] = s;
}

// ---- input projection + BN partial sums ----
__global__ void k_inproj(const float* __restrict__ x, const float* __restrict__ W, const float* __restrict__ b,
                         float* __restrict__ g, float* __restrict__ bns) {
    __shared__ float ls[64], lq[64];
    int t = threadIdx.x;
    if (t < 64) { ls[t] = 0.f; lq[t] = 0.f; }
    __syncthreads();
    int j = t & 63;
    float wcol[F_IN];
#pragma unroll
    for (int k = 0; k < F_IN; k++) wcol[k] = W[k * 64 + j];
    float bias = b[j];
    float sA = 0.f, sQ = 0.f;
    for (int idx = blockIdx.x * blockDim.x + t; idx < NN * 64; idx += gridDim.x * blockDim.x) {
        int node = idx >> 6;
        float acc = bias;
#pragma unroll
        for (int k = 0; k < F_IN; k++) acc += x[node * F_IN + k] * wcol[k];
        g[idx] = acc;
        sA += acc; sQ += acc * acc;
    }
    atomicAdd(&ls[j], sA); atomicAdd(&lq[j], sQ);
    __syncthreads();
    if (t < 64) atomicAdd(&bns[t], ls[t]);
    else if (t < 128) atomicAdd(&bns[t], lq[t - 64]);
}

// ---- BN finalize + ELU (+residual), update h f32 and split-bf16 hi/lo ----
__global__ void k_bnapply(const float* __restrict__ g, const float* __restrict__ bns,
                          const float* __restrict__ gamma, const float* __restrict__ beta,
                          float* h, u16* __restrict__ hbhi, u16* __restrict__ hblo, int residual) {
    int t = blockIdx.x * blockDim.x + threadIdx.x;
    if (t >= NN * 16) return;
    int c4 = (t & 15) * 4;
    float4 gg = *(const float4*)(g + (size_t)t * 4);
    float4 out;
#pragma unroll
    for (int r = 0; r < 4; r++) {
        int c = c4 + r;
        float mean = bns[c] * (1.0f / NN);
        float var = bns[64 + c] * (1.0f / NN) - mean * mean;
        var = fmaxf(var, 0.f);
        float rstd = rsqrtf(var + EPS_BN);
        float v = ((&gg.x)[r] - mean) * rstd * gamma[c] + beta[c];
        (&out.x)[r] = v > 0.f ? v : (__expf(v) - 1.f);
    }
    if (residual) {
        float4 hh = *(const float4*)(h + (size_t)t * 4);
        out.x += hh.x; out.y += hh.y; out.z += hh.z; out.w += hh.w;
    }
    *(float4*)(h + (size_t)t * 4) = out;
    ushort4 phi, plo;
#pragma unroll
    for (int r = 0; r < 4; r++) {
        float v = (&out.x)[r];
        u16 hi = f2bf(v);
        u16 lo = f2bf(v - bf2f(hi));
        (&phi.x)[r] = hi; (&plo.x)[r] = lo;
    }
    *(ushort4*)(hbhi + (size_t)t * 4) = phi;
    *(ushort4*)(hblo + (size_t)t * 4) = plo;
}

// ---- xl|xr GEMM via MFMA, split-bf16 A and B (drop lo*lo) ≈ f32 exact; bf16 out ----
__global__ __launch_bounds__(256) void k_gemm(const u16* __restrict__ hbhi, const u16* __restrict__ hblo,
                                              const u16* __restrict__ WThi, const u16* __restrict__ WTlo,
                                              u16* __restrict__ xlxr) {
    int lane = threadIdx.x & 63;
    int wv = threadIdx.x >> 6;
    int node0 = blockIdx.x * 16;
    int col0 = (blockIdx.y * 4 + wv) * 16;
    int ml = lane & 15;
    int kb = (lane >> 4) * 8;
    size_t arow = (size_t)(node0 + ml) * 64 + kb;
    size_t brow = (size_t)(col0 + ml) * 64 + kb;
    bf16x8 ah0 = *(const bf16x8*)(hbhi + arow);
    bf16x8 ah1 = *(const bf16x8*)(hbhi + arow + 32);
    bf16x8 al0 = *(const bf16x8*)(hblo + arow);
    bf16x8 al1 = *(const bf16x8*)(hblo + arow + 32);
    bf16x8 bh0 = *(const bf16x8*)(WThi + brow);
    bf16x8 bh1 = *(const bf16x8*)(WThi + brow + 32);
    bf16x8 bl0 = *(const bf16x8*)(WTlo + brow);
    bf16x8 bl1 = *(const bf16x8*)(WTlo + brow + 32);
    f32x4 acc = {0.f, 0.f, 0.f, 0.f};
    acc = __builtin_amdgcn_mfma_f32_16x16x32_bf16(al0, bh0, acc, 0, 0, 0);
    acc = __builtin_amdgcn_mfma_f32_16x16x32_bf16(al1, bh1, acc, 0, 0, 0);
    acc = __builtin_amdgcn_mfma_f32_16x16x32_bf16(ah0, bl0, acc, 0, 0, 0);
    acc = __builtin_amdgcn_mfma_f32_16x16x32_bf16(ah1, bl1, acc, 0, 0, 0);
    acc = __builtin_amdgcn_mfma_f32_16x16x32_bf16(ah0, bh0, acc, 0, 0, 0);
    acc = __builtin_amdgcn_mfma_f32_16x16x32_bf16(ah1, bh1, acc, 0, 0, 0);
    int colj = col0 + ml;
    int row = node0 + (lane >> 4) * 4;
#pragma unroll
    for (int r = 0; r < 4; r++) xlxr[(size_t)(row + r) * 256 + colj] = f2bf(acc[r]);
}

// ---- GATv2 attention: wave per dst, online softmax over packed-bf16 xlxr ----
__global__ __launch_bounds__(256) void k_edge(const unsigned int* __restrict__ xw, const int* __restrict__ rp,
                                              const int* __restrict__ col, const float* __restrict__ attL,
                                              const float* __restrict__ cbL, float* __restrict__ g,
                                              float* __restrict__ bns) {
    __shared__ float ls[64], lq[64];
    int t = threadIdx.x;
    if (t < 64) { ls[t] = 0.f; lq[t] = 0.f; }
    __syncthreads();
    int lane = t & 63;
    int wid = blockIdx.x * 4 + (t >> 6);
    int nw = gridDim.x * 4;
    float at0 = attL[2 * lane];
    float at1 = attL[2 * lane + 1];
    float cb0 = 0.f, cb1 = 0.f;
    if (lane < 32) { cb0 = cbL[2 * lane]; cb1 = cbL[2 * lane + 1]; }
    float s0acc = 0.f, s1acc = 0.f, q0acc = 0.f, q1acc = 0.f;
    for (int d = wid; d < NN; d += nw) {
        // row d: 128 dwords; xl = dwords 0..63 (channels 2l,2l+1), xr = dwords 64..127
        float2 xr2 = bf2x(xw[(size_t)d * 128 + 64 + lane]);
        int beg = rp[d], end = rp[d + 1];
        int s = col[beg];
        if ((unsigned)s >= NN) s = 0;
        float2 xl = bf2x(xw[(size_t)s * 128 + lane]);
        float m = -1e30f, lsum = 0.f, a0c = 0.f, a1c = 0.f;
        for (int q = beg; q < end; q++) {
            float a0 = xl.x, a1 = xl.y;
            if (q + 1 < end) {
                int s2 = col[q + 1];
                if ((unsigned)s2 >= NN) s2 = 0;
                xl = bf2x(xw[(size_t)s2 * 128 + lane]);
            }
            float u0 = a0 + xr2.x, u1 = a1 + xr2.y;
            float l0 = u0 > 0.f ? u0 : 0.2f * u0;
            float l1 = u1 > 0.f ? u1 : 0.2f * u1;
            float e = l0 * at0 + l1 * at1;
            e += __shfl_xor(e, 1); e += __shfl_xor(e, 2); e += __shfl_xor(e, 4);
            e += __shfl_xor(e, 8); e += __shfl_xor(e, 16);
            float mn = fmaxf(m, e);
            float sc = __expf(m - mn);
            float pw = __expf(e - mn);
            lsum = lsum * sc + pw;
            a0c = a0c * sc + pw * a0;
            a1c = a1c * sc + pw * a1;
            m = mn;
        }
        float inv = 1.0f / (lsum + 1e-16f);
        float v0 = a0c * inv, v1 = a1c * inv;
        float w0 = 0.5f * (v0 + __shfl_xor(v0, 32));
        float w1 = 0.5f * (v1 + __shfl_xor(v1, 32));
        if (lane < 32) {
            float c0 = w0 + cb0, c1 = w1 + cb1;
            float2 o; o.x = c0; o.y = c1;
            *(float2*)(g + (size_t)d * 64 + 2 * lane) = o;
            s0acc += c0; q0acc += c0 * c0;
            s1acc += c1; q1acc += c1 * c1;
        }
    }
    if (lane < 32) {
        atomicAdd(&ls[2 * lane], s0acc); atomicAdd(&ls[2 * lane + 1], s1acc);
        atomicAdd(&lq[2 * lane], q0acc); atomicAdd(&lq[2 * lane + 1], q1acc);
    }
    __syncthreads();
    if (t < 64) atomicAdd(&bns[t], ls[t]);
    else if (t < 128) atomicAdd(&bns[t], lq[t - 64]);
}

// ---- output head: half-wave per node, fused MLP + sigmoid, f32 out ----
__global__ void k_head(const float* __restrict__ h, const float* __restrict__ W1, const float* __restrict__ b1,
                       const float* __restrict__ W2, const float* __restrict__ b2, float* __restrict__ out) {
    int t = blockIdx.x * blockDim.x + threadIdx.x;
    int node = t >> 5;
    int j = t & 31;
    if (node >= NN) return;
    float acc = b1[j];
    const float* hr = h + (size_t)node * 64;
#pragma unroll
    for (int k = 0; k < 64; k++) acc += hr[k] * W1[k * 32 + j];
    float e = acc > 0.f ? acc : (__expf(acc) - 1.f);
    float z = e * W2[j];
    z += __shfl_xor(z, 1); z += __shfl_xor(z, 2); z += __shfl_xor(z, 4);
    z += __shfl_xor(z, 8); z += __shfl_xor(z, 16);
    if (j == 0) {
        float y = z + b2[0];
        out[node] = 1.0f / (1.0f + __expf(-y));
    }
}

extern "C" void kernel_launch(void* const* d_in, const int* in_sizes, int n_in,
                              void* d_out, int out_size, void* d_ws, size_t ws_size,
                              hipStream_t stream) {
    const float* x = (const float*)d_in[0];
    const int* ei = (const int*)d_in[1];
    const float* inW = (const float*)d_in[2];
    const float* inb = (const float*)d_in[3];
    const float* ing = (const float*)d_in[4];
    const float* inbeta = (const float*)d_in[5];
    const float* Wl = (const float*)d_in[6];
    const float* Wr = (const float*)d_in[7];
    const float* att = (const float*)d_in[8];
    const float* cb = (const float*)d_in[9];
    const float* bng = (const float*)d_in[10];
    const float* bnb = (const float*)d_in[11];
    const float* W1 = (const float*)d_in[12];
    const float* b1 = (const float*)d_in[13];
    const float* W2 = (const float*)d_in[14];
    const float* b2 = (const float*)d_in[15];
    float* out = (float*)d_out;

    char* ws = (char*)d_ws;
    size_t off = 0;
    auto alloc = [&](size_t bytes) -> char* {
        char* p = ws + off;
        off = (off + bytes + 255) & ~(size_t)255;
        return p;
    };
    float* h    = (float*)alloc((size_t)NN * 64 * 4);
    float* g    = (float*)alloc((size_t)NN * 64 * 4);
    u16* xlxr   = (u16*)alloc((size_t)NN * 256 * 2);   // bf16 packed
    u16* hbhi   = (u16*)alloc((size_t)NN * 64 * 2);
    u16* hblo   = (u16*)alloc((size_t)NN * 64 * 2);
    u16* WThi   = (u16*)alloc((size_t)NLAYERS * 256 * 64 * 2);
    u16* WTlo   = (u16*)alloc((size_t)NLAYERS * 256 * 64 * 2);
    int* deg    = (int*)alloc((size_t)NN * 4);
    int* rp     = (int*)alloc((size_t)(NN + 1) * 4);
    int* cur    = (int*)alloc((size_t)NN * 4);
    int* colv   = (int*)alloc((size_t)NET * 4);
    int* stmp   = (int*)alloc((size_t)NN * 4);
    int* part   = (int*)alloc(256 * 4);
    float* bns  = (float*)alloc((size_t)(NLAYERS + 1) * 128 * 4);

    k_zero_i<<<(NN + 255) / 256, 256, 0, stream>>>(deg, NN);
    k_zero_f<<<((NLAYERS + 1) * 128 + 255) / 256, 256, 0, stream>>>(bns, (NLAYERS + 1) * 128);

    k_wt<<<(NLAYERS * 256 * HIDC + 255) / 256, 256, 0, stream>>>(Wl, Wr, WThi, WTlo);
    k_count<<<(NE + 255) / 256, 256, 0, stream>>>(ei, deg);
    k_scan1<<<196, 256, 0, stream>>>(deg, stmp, part);
    k_scan2<<<1, 256, 0, stream>>>(part);
    k_scan3<<<196, 256, 0, stream>>>(deg, stmp, part, rp, cur);
    k_scatter<<<(NET + 255) / 256, 256, 0, stream>>>(ei, cur, colv);

    k_inproj<<<512, 256, 0, stream>>>(x, inW, inb, g, bns);
    k_bnapply<<<3125, 256, 0, stream>>>(g, bns, ing, inbeta, h, hbhi, hblo, 0);

    for (int i = 0; i < NLAYERS; i++) {
        k_gemm<<<dim3(3125, 4), 256, 0, stream>>>(hbhi, hblo, WThi + (size_t)i * 16384,
                                                  WTlo + (size_t)i * 16384, xlxr);
        k_edge<<<2048, 256, 0, stream>>>((const unsigned int*)xlxr, rp, colv,
                                         att + (size_t)i * 128, cb + (size_t)i * 64,
                                         g, bns + (size_t)(i + 1) * 128);
        k_bnapply<<<3125, 256, 0, stream>>>(g, bns + (size_t)(i + 1) * 128, bng + (size_t)i * 64,
                                            bnb + (size_t)i * 64, h, hbhi, hblo, 1);
    }
    k_head<<<6250, 256, 0, stream>>>(h, W1, b1, W2, b2, out);
}

// Round 6
// 1706.885 us; speedup vs baseline: 1.3993x; 1.1898x over previous
//
#include <hip/hip_runtime.h>

#define NN 50000
#define F_IN 17
#define HIDC 64
#define NLAYERS 12
#define NE 400000
#define NET (NE + NN)
#define EPS_BN 1e-5f

typedef unsigned short u16;
typedef __bf16 bf16x8 __attribute__((ext_vector_type(8)));
typedef float f32x4 __attribute__((ext_vector_type(4)));

__device__ __forceinline__ float bf2f(u16 v) {
    union { unsigned int i; float f; } u; u.i = ((unsigned int)v) << 16; return u.f;
}
__device__ __forceinline__ u16 f2bf(float f) {
    union { float f; unsigned int i; } u; u.f = f;
    unsigned int r = u.i + 0x7fffu + ((u.i >> 16) & 1u);
    return (u16)(r >> 16);
}
// unpack 2 packed bf16 (low u16 = even channel) to floats
__device__ __forceinline__ float2 bf2x(unsigned int w) {
    union { unsigned int i; float f; } a, b;
    a.i = w << 16; b.i = w & 0xffff0000u;
    float2 r; r.x = a.f; r.y = b.f; return r;
}
__device__ __forceinline__ void unpack8(uint4 w, float* f) {
    float2 a = bf2x(w.x), b = bf2x(w.y), c = bf2x(w.z), d = bf2x(w.w);
    f[0] = a.x; f[1] = a.y; f[2] = b.x; f[3] = b.y;
    f[4] = c.x; f[5] = c.y; f[6] = d.x; f[7] = d.y;
}

__global__ void k_zero_i(int* __restrict__ p, int n) {
    int i = blockIdx.x * blockDim.x + threadIdx.x;
    if (i < n) p[i] = 0;
}
__global__ void k_zero_f(float* __restrict__ p, int n) {
    int i = blockIdx.x * blockDim.x + threadIdx.x;
    if (i < n) p[i] = 0.f;
}

// ---- transposed split-bf16 concat weights: WT[i][j][k] = (j<128?Wl:Wr)[i][k][j'] ----
__global__ void k_wt(const float* __restrict__ Wl, const float* __restrict__ Wr,
                     u16* __restrict__ WThi, u16* __restrict__ WTlo) {
    int t = blockIdx.x * blockDim.x + threadIdx.x;
    if (t >= NLAYERS * 256 * HIDC) return;
    int k = t & 63, j = (t >> 6) & 255, i = t >> 14;
    int jj = (j < 128) ? j : (j - 128);
    float v = (j < 128) ? Wl[(i * HIDC + k) * 128 + jj] : Wr[(i * HIDC + k) * 128 + jj];
    u16 hi = f2bf(v);
    u16 lo = f2bf(v - bf2f(hi));
    WThi[t] = hi; WTlo[t] = lo;
}

// ---- CSR build ----
__global__ void k_count(const int* __restrict__ ei, int* __restrict__ deg) {
    int e = blockIdx.x * blockDim.x + threadIdx.x;
    if (e < NE) {
        int d = ei[NE + e];
        if ((unsigned)d < NN) atomicAdd(&deg[d], 1);
    }
}

// 2-level scan
__global__ void k_scan1(const int* __restrict__ deg, int* __restrict__ tmp, int* __restrict__ part) {
    __shared__ int s[256];
    int b = blockIdx.x, t = threadIdx.x;
    int n = b * 256 + t;
    int v = (n < NN) ? deg[n] + 1 : 0;
    s[t] = v; __syncthreads();
    for (int o = 1; o < 256; o <<= 1) {
        int a = s[t];
        int w = (t >= o) ? s[t - o] : 0;
        __syncthreads();
        s[t] = a + w;
        __syncthreads();
    }
    if (n < NN) tmp[n] = s[t];
    if (t == 255) part[b] = s[255];
}
__global__ void k_scan2(int* __restrict__ part) {
    __shared__ int s[256];
    int t = threadIdx.x;
    int v = (t < 196) ? part[t] : 0;
    s[t] = v; __syncthreads();
    for (int o = 1; o < 256; o <<= 1) {
        int a = s[t];
        int w = (t >= o) ? s[t - o] : 0;
        __syncthreads();
        s[t] = a + w;
        __syncthreads();
    }
    if (t < 196) part[t] = s[t] - v;
    if (t == 195) part[196] = s[195];
}
__global__ void k_scan3(const int* __restrict__ deg, const int* __restrict__ tmp,
                        const int* __restrict__ part, int* __restrict__ rp, int* __restrict__ cur) {
    int b = blockIdx.x, t = threadIdx.x;
    int n = b * 256 + t;
    if (n < NN) {
        int e = tmp[n] - (deg[n] + 1) + part[b];
        rp[n] = e; cur[n] = e;
    }
    if (n == 0) rp[NN] = part[196];
}

__global__ void k_scatter(const int* __restrict__ ei, int* __restrict__ cur, int* __restrict__ col) {
    int e = blockIdx.x * blockDim.x + threadIdx.x;
    if (e >= NET) return;
    int s, d;
    if (e < NE) { s = ei[e]; d = ei[NE + e]; } else { s = d = e - NE; }
    if ((unsigned)s >= NN) s = 0;
    if ((unsigned)d >= NN) d = 0;
    int p = atomicAdd(&cur[d], 1);
    if ((unsigned)p < NET) col[p] = s;
}

// ---- input projection + BN partial sums ----
__global__ void k_inproj(const float* __restrict__ x, const float* __restrict__ W, const float* __restrict__ b,
                         float* __restrict__ g, float* __restrict__ bns) {
    __shared__ float ls[64], lq[64];
    int t = threadIdx.x;
    if (t < 64) { ls[t] = 0.f; lq[t] = 0.f; }
    __syncthreads();
    int j = t & 63;
    float wcol[F_IN];
#pragma unroll
    for (int k = 0; k < F_IN; k++) wcol[k] = W[k * 64 + j];
    float bias = b[j];
    float sA = 0.f, sQ = 0.f;
    for (int idx = blockIdx.x * blockDim.x + t; idx < NN * 64; idx += gridDim.x * blockDim.x) {
        int node = idx >> 6;
        float acc = bias;
#pragma unroll
        for (int k = 0; k < F_IN; k++) acc += x[node * F_IN + k] * wcol[k];
        g[idx] = acc;
        sA += acc; sQ += acc * acc;
    }
    atomicAdd(&ls[j], sA); atomicAdd(&lq[j], sQ);
    __syncthreads();
    if (t < 64) atomicAdd(&bns[t], ls[t]);
    else if (t < 128) atomicAdd(&bns[t], lq[t - 64]);
}

// ---- BN finalize + ELU (+residual), update h f32 and split-bf16 hi/lo ----
__global__ void k_bnapply(const float* __restrict__ g, const float* __restrict__ bns,
                          const float* __restrict__ gamma, const float* __restrict__ beta,
                          float* h, u16* __restrict__ hbhi, u16* __restrict__ hblo, int residual) {
    int t = blockIdx.x * blockDim.x + threadIdx.x;
    if (t >= NN * 16) return;
    int c4 = (t & 15) * 4;
    float4 gg = *(const float4*)(g + (size_t)t * 4);
    float4 out;
#pragma unroll
    for (int r = 0; r < 4; r++) {
        int c = c4 + r;
        float mean = bns[c] * (1.0f / NN);
        float var = bns[64 + c] * (1.0f / NN) - mean * mean;
        var = fmaxf(var, 0.f);
        float rstd = rsqrtf(var + EPS_BN);
        float v = ((&gg.x)[r] - mean) * rstd * gamma[c] + beta[c];
        (&out.x)[r] = v > 0.f ? v : (__expf(v) - 1.f);
    }
    if (residual) {
        float4 hh = *(const float4*)(h + (size_t)t * 4);
        out.x += hh.x; out.y += hh.y; out.z += hh.z; out.w += hh.w;
    }
    *(float4*)(h + (size_t)t * 4) = out;
    ushort4 phi, plo;
#pragma unroll
    for (int r = 0; r < 4; r++) {
        float v = (&out.x)[r];
        u16 hi = f2bf(v);
        u16 lo = f2bf(v - bf2f(hi));
        (&phi.x)[r] = hi; (&plo.x)[r] = lo;
    }
    *(ushort4*)(hbhi + (size_t)t * 4) = phi;
    *(ushort4*)(hblo + (size_t)t * 4) = plo;
}

// ---- xl|xr GEMM via MFMA, split-bf16 A and B (drop lo*lo) ≈ f32 exact; bf16 out ----
__global__ __launch_bounds__(256) void k_gemm(const u16* __restrict__ hbhi, const u16* __restrict__ hblo,
                                              const u16* __restrict__ WThi, const u16* __restrict__ WTlo,
                                              u16* __restrict__ xlxr) {
    int lane = threadIdx.x & 63;
    int wv = threadIdx.x >> 6;
    int node0 = blockIdx.x * 16;
    int col0 = (blockIdx.y * 4 + wv) * 16;
    int ml = lane & 15;
    int kb = (lane >> 4) * 8;
    size_t arow = (size_t)(node0 + ml) * 64 + kb;
    size_t brow = (size_t)(col0 + ml) * 64 + kb;
    bf16x8 ah0 = *(const bf16x8*)(hbhi + arow);
    bf16x8 ah1 = *(const bf16x8*)(hbhi + arow + 32);
    bf16x8 al0 = *(const bf16x8*)(hblo + arow);
    bf16x8 al1 = *(const bf16x8*)(hblo + arow + 32);
    bf16x8 bh0 = *(const bf16x8*)(WThi + brow);
    bf16x8 bh1 = *(const bf16x8*)(WThi + brow + 32);
    bf16x8 bl0 = *(const bf16x8*)(WTlo + brow);
    bf16x8 bl1 = *(const bf16x8*)(WTlo + brow + 32);
    f32x4 acc = {0.f, 0.f, 0.f, 0.f};
    acc = __builtin_amdgcn_mfma_f32_16x16x32_bf16(al0, bh0, acc, 0, 0, 0);
    acc = __builtin_amdgcn_mfma_f32_16x16x32_bf16(al1, bh1, acc, 0, 0, 0);
    acc = __builtin_amdgcn_mfma_f32_16x16x32_bf16(ah0, bl0, acc, 0, 0, 0);
    acc = __builtin_amdgcn_mfma_f32_16x16x32_bf16(ah1, bl1, acc, 0, 0, 0);
    acc = __builtin_amdgcn_mfma_f32_16x16x32_bf16(ah0, bh0, acc, 0, 0, 0);
    acc = __builtin_amdgcn_mfma_f32_16x16x32_bf16(ah1, bh1, acc, 0, 0, 0);
    int colj = col0 + ml;
    int row = node0 + (lane >> 4) * 4;
#pragma unroll
    for (int r = 0; r < 4; r++) xlxr[(size_t)(row + r) * 256 + colj] = f2bf(acc[r]);
}

// ---- GATv2 attention v2: wave per dst, 4x16-lane edge subsets, flash-merge ----
// lane = 16*gsub + q; lane handles channels 8q..8q+7 (uint4 = 4 dwords = 8 bf16)
// q<8 -> head 0 (ch 0..63), q>=8 -> head 1 (ch 64..127)
__global__ __launch_bounds__(256) void k_edge(const uint4* __restrict__ xw4, const int* __restrict__ rp,
                                              const int* __restrict__ col, const float* __restrict__ attL,
                                              const float* __restrict__ cbL, float* __restrict__ g,
                                              float* __restrict__ bns) {
    __shared__ float ls[64], lq[64];
    int t = threadIdx.x;
    if (t < 64) { ls[t] = 0.f; lq[t] = 0.f; }
    __syncthreads();
    int lane = t & 63;
    int q = lane & 15;
    int gsub = lane >> 4;
    int wid = blockIdx.x * 4 + (t >> 6);
    int nw = gridDim.x * 4;
    float atv[8];
#pragma unroll
    for (int i = 0; i < 8; i++) atv[i] = attL[8 * q + i];
    float cbv[8];
#pragma unroll
    for (int i = 0; i < 8; i++) cbv[i] = 0.f;
    if (q < 8) {
#pragma unroll
        for (int i = 0; i < 8; i++) cbv[i] = cbL[8 * q + i];
    }
    float sacc[8], qacc[8];
#pragma unroll
    for (int i = 0; i < 8; i++) { sacc[i] = 0.f; qacc[i] = 0.f; }
    for (int d = wid; d < NN; d += nw) {
        // xr for this dst: uint4 index d*32 + 16 + q
        float xr[8];
        { uint4 w = xw4[(size_t)d * 32 + 16 + q]; unpack8(w, xr); }
        int beg = rp[d], end = rp[d + 1];
        float m = -1e30f, lsum = 0.f;
        float acc[8];
#pragma unroll
        for (int i = 0; i < 8; i++) acc[i] = 0.f;
        int idx = beg + gsub;
        int s0 = (idx < end) ? col[idx] : 0;
        if ((unsigned)s0 >= NN) s0 = 0;
        uint4 xlw = xw4[(size_t)s0 * 32 + q];
        for (; idx < end; idx += 4) {
            uint4 curw = xlw;
            int nidx = idx + 4;
            if (nidx < end) {
                int s2 = col[nidx];
                if ((unsigned)s2 >= NN) s2 = 0;
                xlw = xw4[(size_t)s2 * 32 + q];
            }
            float xl[8]; unpack8(curw, xl);
            float p = 0.f;
#pragma unroll
            for (int i = 0; i < 8; i++) {
                float u = xl[i] + xr[i];
                float lr = u > 0.f ? u : 0.2f * u;
                p += lr * atv[i];
            }
            // reduce over 8-lane head group within subset
            p += __shfl_xor(p, 1); p += __shfl_xor(p, 2); p += __shfl_xor(p, 4);
            float mn = fmaxf(m, p);
            float sc = __expf(m - mn);
            float pw = __expf(p - mn);
            lsum = lsum * sc + pw;
#pragma unroll
            for (int i = 0; i < 8; i++) acc[i] = acc[i] * sc + pw * xl[i];
            m = mn;
        }
        // merge 4 subsets: xor 16, then xor 32 (q preserved -> channels aligned)
#pragma unroll
        for (int off = 16; off <= 32; off <<= 1) {
            float mo = __shfl_xor(m, off);
            float lo = __shfl_xor(lsum, off);
            float mn = fmaxf(m, mo);
            float sa = __expf(m - mn), sb = __expf(mo - mn);
            lsum = lsum * sa + lo * sb;
#pragma unroll
            for (int i = 0; i < 8; i++) {
                float ao = __shfl_xor(acc[i], off);
                acc[i] = acc[i] * sa + ao * sb;
            }
            m = mn;
        }
        float inv = 1.0f / (lsum + 1e-16f);
        // head average: lane q and q^8 hold matching channels of head0/head1
#pragma unroll
        for (int i = 0; i < 8; i++) {
            float v = acc[i] * inv;
            acc[i] = 0.5f * (v + __shfl_xor(v, 8));
        }
        if (gsub == 0 && q < 8) {
            float4 w0, w1;
#pragma unroll
            for (int i = 0; i < 8; i++) {
                float c = acc[i] + cbv[i];
                sacc[i] += c; qacc[i] += c * c;
                if (i < 4) (&w0.x)[i] = c; else (&w1.x)[i - 4] = c;
            }
            *(float4*)(g + (size_t)d * 64 + 8 * q) = w0;
            *(float4*)(g + (size_t)d * 64 + 8 * q + 4) = w1;
        }
    }
    if (gsub == 0 && q < 8) {
#pragma unroll
        for (int i = 0; i < 8; i++) {
            atomicAdd(&ls[8 * q + i], sacc[i]);
            atomicAdd(&lq[8 * q + i], qacc[i]);
        }
    }
    __syncthreads();
    if (t < 64) atomicAdd(&bns[t], ls[t]);
    else if (t < 128) atomicAdd(&bns[t], lq[t - 64]);
}

// ---- output head: half-wave per node, fused MLP + sigmoid, f32 out ----
__global__ void k_head(const float* __restrict__ h, const float* __restrict__ W1, const float* __restrict__ b1,
                       const float* __restrict__ W2, const float* __restrict__ b2, float* __restrict__ out) {
    int t = blockIdx.x * blockDim.x + threadIdx.x;
    int node = t >> 5;
    int j = t & 31;
    if (node >= NN) return;
    float acc = b1[j];
    const float* hr = h + (size_t)node * 64;
#pragma unroll
    for (int k = 0; k < 64; k++) acc += hr[k] * W1[k * 32 + j];
    float e = acc > 0.f ? acc : (__expf(acc) - 1.f);
    float z = e * W2[j];
    z += __shfl_xor(z, 1); z += __shfl_xor(z, 2); z += __shfl_xor(z, 4);
    z += __shfl_xor(z, 8); z += __shfl_xor(z, 16);
    if (j == 0) {
        float y = z + b2[0];
        out[node] = 1.0f / (1.0f + __expf(-y));
    }
}

extern "C" void kernel_launch(void* const* d_in, const int* in_sizes, int n_in,
                              void* d_out, int out_size, void* d_ws, size_t ws_size,
                              hipStream_t stream) {
    const float* x = (const float*)d_in[0];
    const int* ei = (const int*)d_in[1];
    const float* inW = (const float*)d_in[2];
    const float* inb = (const float*)d_in[3];
    const float* ing = (const float*)d_in[4];
    const float* inbeta = (const float*)d_in[5];
    const float* Wl = (const float*)d_in[6];
    const float* Wr = (const float*)d_in[7];
    const float* att = (const float*)d_in[8];
    const float* cb = (const float*)d_in[9];
    const float* bng = (const float*)d_in[10];
    const float* bnb = (const float*)d_in[11];
    const float* W1 = (const float*)d_in[12];
    const float* b1 = (const float*)d_in[13];
    const float* W2 = (const float*)d_in[14];
    const float* b2 = (const float*)d_in[15];
    float* out = (float*)d_out;

    char* ws = (char*)d_ws;
    size_t off = 0;
    auto alloc = [&](size_t bytes) -> char* {
        char* p = ws + off;
        off = (off + bytes + 255) & ~(size_t)255;
        return p;
    };
    float* h    = (float*)alloc((size_t)NN * 64 * 4);
    float* g    = (float*)alloc((size_t)NN * 64 * 4);
    u16* xlxr   = (u16*)alloc((size_t)NN * 256 * 2);   // bf16 packed
    u16* hbhi   = (u16*)alloc((size_t)NN * 64 * 2);
    u16* hblo   = (u16*)alloc((size_t)NN * 64 * 2);
    u16* WThi   = (u16*)alloc((size_t)NLAYERS * 256 * 64 * 2);
    u16* WTlo   = (u16*)alloc((size_t)NLAYERS * 256 * 64 * 2);
    int* deg    = (int*)alloc((size_t)NN * 4);
    int* rp     = (int*)alloc((size_t)(NN + 1) * 4);
    int* cur    = (int*)alloc((size_t)NN * 4);
    int* colv   = (int*)alloc((size_t)NET * 4);
    int* stmp   = (int*)alloc((size_t)NN * 4);
    int* part   = (int*)alloc(256 * 4);
    float* bns  = (float*)alloc((size_t)(NLAYERS + 1) * 128 * 4);

    k_zero_i<<<(NN + 255) / 256, 256, 0, stream>>>(deg, NN);
    k_zero_f<<<((NLAYERS + 1) * 128 + 255) / 256, 256, 0, stream>>>(bns, (NLAYERS + 1) * 128);

    k_wt<<<(NLAYERS * 256 * HIDC + 255) / 256, 256, 0, stream>>>(Wl, Wr, WThi, WTlo);
    k_count<<<(NE + 255) / 256, 256, 0, stream>>>(ei, deg);
    k_scan1<<<196, 256, 0, stream>>>(deg, stmp, part);
    k_scan2<<<1, 256, 0, stream>>>(part);
    k_scan3<<<196, 256, 0, stream>>>(deg, stmp, part, rp, cur);
    k_scatter<<<(NET + 255) / 256, 256, 0, stream>>>(ei, cur, colv);

    k_inproj<<<512, 256, 0, stream>>>(x, inW, inb, g, bns);
    k_bnapply<<<3125, 256, 0, stream>>>(g, bns, ing, inbeta, h, hbhi, hblo, 0);

    for (int i = 0; i < NLAYERS; i++) {
        k_gemm<<<dim3(3125, 4), 256, 0, stream>>>(hbhi, hblo, WThi + (size_t)i * 16384,
                                                  WTlo + (size_t)i * 16384, xlxr);
        k_edge<<<2048, 256, 0, stream>>>((const uint4*)xlxr, rp, colv,
                                         att + (size_t)i * 128, cb + (size_t)i * 64,
                                         g, bns + (size_t)(i + 1) * 128);
        k_bnapply<<<3125, 256, 0, stream>>>(g, bns + (size_t)(i + 1) * 128, bng + (size_t)i * 64,
                                            bnb + (size_t)i * 64, h, hbhi, hblo, 1);
    }
    k_head<<<6250, 256, 0, stream>>>(h, W1, b1, W2, b2, out);
}

// Round 7
// 1403.053 us; speedup vs baseline: 1.7024x; 1.2166x over previous
//
#include <hip/hip_runtime.h>

#define NN 50000
#define F_IN 17
#define HIDC 64
#define NLAYERS 12
#define NE 400000
#define NET (NE + NN)
#define EPS_BN 1e-5f

typedef unsigned short u16;
typedef __bf16 bf16x8 __attribute__((ext_vector_type(8)));
typedef float f32x4 __attribute__((ext_vector_type(4)));

__device__ __forceinline__ float bf2f(u16 v) {
    union { unsigned int i; float f; } u; u.i = ((unsigned int)v) << 16; return u.f;
}
__device__ __forceinline__ u16 f2bf(float f) {
    union { float f; unsigned int i; } u; u.f = f;
    unsigned int r = u.i + 0x7fffu + ((u.i >> 16) & 1u);
    return (u16)(r >> 16);
}
__device__ __forceinline__ float2 bf2x(unsigned int w) {
    union { unsigned int i; float f; } a, b;
    a.i = w << 16; b.i = w & 0xffff0000u;
    float2 r; r.x = a.f; r.y = b.f; return r;
}
__device__ __forceinline__ void unpack8(uint4 w, float* f) {
    float2 a = bf2x(w.x), b = bf2x(w.y), c = bf2x(w.z), d = bf2x(w.w);
    f[0] = a.x; f[1] = a.y; f[2] = b.x; f[3] = b.y;
    f[4] = c.x; f[5] = c.y; f[6] = d.x; f[7] = d.y;
}

__global__ void k_zero_i(int* __restrict__ p, int n) {
    int i = blockIdx.x * blockDim.x + threadIdx.x;
    if (i < n) p[i] = 0;
}
__global__ void k_zero_f(float* __restrict__ p, int n) {
    int i = blockIdx.x * blockDim.x + threadIdx.x;
    if (i < n) p[i] = 0.f;
}

// ---- transposed split-bf16 concat weights ----
__global__ void k_wt(const float* __restrict__ Wl, const float* __restrict__ Wr,
                     u16* __restrict__ WThi, u16* __restrict__ WTlo) {
    int t = blockIdx.x * blockDim.x + threadIdx.x;
    if (t >= NLAYERS * 256 * HIDC) return;
    int k = t & 63, j = (t >> 6) & 255, i = t >> 14;
    int jj = (j < 128) ? j : (j - 128);
    float v = (j < 128) ? Wl[(i * HIDC + k) * 128 + jj] : Wr[(i * HIDC + k) * 128 + jj];
    u16 hi = f2bf(v);
    u16 lo = f2bf(v - bf2f(hi));
    WThi[t] = hi; WTlo[t] = lo;
}

// ---- CSR build ----
__global__ void k_count(const int* __restrict__ ei, int* __restrict__ deg) {
    int e = blockIdx.x * blockDim.x + threadIdx.x;
    if (e < NE) {
        int d = ei[NE + e];
        if ((unsigned)d < NN) atomicAdd(&deg[d], 1);
    }
}

__global__ void k_scan1(const int* __restrict__ deg, int* __restrict__ tmp, int* __restrict__ part) {
    __shared__ int s[256];
    int b = blockIdx.x, t = threadIdx.x;
    int n = b * 256 + t;
    int v = (n < NN) ? deg[n] + 1 : 0;
    s[t] = v; __syncthreads();
    for (int o = 1; o < 256; o <<= 1) {
        int a = s[t];
        int w = (t >= o) ? s[t - o] : 0;
        __syncthreads();
        s[t] = a + w;
        __syncthreads();
    }
    if (n < NN) tmp[n] = s[t];
    if (t == 255) part[b] = s[255];
}
__global__ void k_scan2(int* __restrict__ part) {
    __shared__ int s[256];
    int t = threadIdx.x;
    int v = (t < 196) ? part[t] : 0;
    s[t] = v; __syncthreads();
    for (int o = 1; o < 256; o <<= 1) {
        int a = s[t];
        int w = (t >= o) ? s[t - o] : 0;
        __syncthreads();
        s[t] = a + w;
        __syncthreads();
    }
    if (t < 196) part[t] = s[t] - v;
    if (t == 195) part[196] = s[195];
}
__global__ void k_scan3(const int* __restrict__ deg, const int* __restrict__ tmp,
                        const int* __restrict__ part, int* __restrict__ rp, int* __restrict__ cur) {
    int b = blockIdx.x, t = threadIdx.x;
    int n = b * 256 + t;
    if (n < NN) {
        int e = tmp[n] - (deg[n] + 1) + part[b];
        rp[n] = e; cur[n] = e;
    }
    if (n == 0) rp[NN] = part[196];
}

__global__ void k_scatter(const int* __restrict__ ei, int* __restrict__ cur, int* __restrict__ col) {
    int e = blockIdx.x * blockDim.x + threadIdx.x;
    if (e >= NET) return;
    int s, d;
    if (e < NE) { s = ei[e]; d = ei[NE + e]; } else { s = d = e - NE; }
    if ((unsigned)s >= NN) s = 0;
    if ((unsigned)d >= NN) d = 0;
    int p = atomicAdd(&cur[d], 1);
    if ((unsigned)p < NET) col[p] = s;
}

// ---- input projection + BN partial sums ----
__global__ void k_inproj(const float* __restrict__ x, const float* __restrict__ W, const float* __restrict__ b,
                         float* __restrict__ g, float* __restrict__ bns) {
    __shared__ float ls[64], lq[64];
    int t = threadIdx.x;
    if (t < 64) { ls[t] = 0.f; lq[t] = 0.f; }
    __syncthreads();
    int j = t & 63;
    float wcol[F_IN];
#pragma unroll
    for (int k = 0; k < F_IN; k++) wcol[k] = W[k * 64 + j];
    float bias = b[j];
    float sA = 0.f, sQ = 0.f;
    for (int idx = blockIdx.x * blockDim.x + t; idx < NN * 64; idx += gridDim.x * blockDim.x) {
        int node = idx >> 6;
        float acc = bias;
#pragma unroll
        for (int k = 0; k < F_IN; k++) acc += x[node * F_IN + k] * wcol[k];
        g[idx] = acc;
        sA += acc; sQ += acc * acc;
    }
    atomicAdd(&ls[j], sA); atomicAdd(&lq[j], sQ);
    __syncthreads();
    if (t < 64) atomicAdd(&bns[t], ls[t]);
    else if (t < 128) atomicAdd(&bns[t], lq[t - 64]);
}

// ---- fused BN+ELU+residual prologue + xl|xr MFMA GEMM ----
// block = 16-node tile x all 256 cols; 4 waves, each wave 4 col-tiles
#define LDP 72  // LDS row stride in u16 (pad 64->72: 2-way bank aliasing = free)
__global__ __launch_bounds__(256) void k_gemmbn(const float* __restrict__ g, const float* __restrict__ bns,
                                                const float* __restrict__ gamma, const float* __restrict__ beta,
                                                float* h, int residual,
                                                const u16* __restrict__ WThi, const u16* __restrict__ WTlo,
                                                u16* __restrict__ xlxr) {
    __shared__ u16 shi[16 * LDP];
    __shared__ u16 slo[16 * LDP];
    int t = threadIdx.x;
    int node0 = blockIdx.x * 16;
    int lane = t & 63, wv = t >> 6;
    int ml = lane & 15, kb = (lane >> 4) * 8;
    // B fragments for this wave's 4 col-tiles (independent of LDS)
    bf16x8 bh[4][2], bl[4][2];
#pragma unroll
    for (int c = 0; c < 4; c++) {
        int col0 = (wv * 4 + c) * 16;
        size_t brow = (size_t)(col0 + ml) * 64 + kb;
        bh[c][0] = *(const bf16x8*)(WThi + brow);
        bh[c][1] = *(const bf16x8*)(WThi + brow + 32);
        bl[c][0] = *(const bf16x8*)(WTlo + brow);
        bl[c][1] = *(const bf16x8*)(WTlo + brow + 32);
    }
    // BN+ELU+residual for the 16-node tile: thread t -> node t>>4, ch (t&15)*4
    {
        int nd = t >> 4, ch = (t & 15) * 4;
        size_t gpos = (size_t)(node0 + nd) * 64 + ch;
        float4 gg = *(const float4*)(g + gpos);
        float4 out;
#pragma unroll
        for (int r = 0; r < 4; r++) {
            int c = ch + r;
            float mean = bns[c] * (1.0f / NN);
            float var = bns[64 + c] * (1.0f / NN) - mean * mean;
            var = fmaxf(var, 0.f);
            float rstd = rsqrtf(var + EPS_BN);
            float v = ((&gg.x)[r] - mean) * rstd * gamma[c] + beta[c];
            (&out.x)[r] = v > 0.f ? v : (__expf(v) - 1.f);
        }
        if (residual) {
            float4 hh = *(const float4*)(h + gpos);
            out.x += hh.x; out.y += hh.y; out.z += hh.z; out.w += hh.w;
        }
        *(float4*)(h + gpos) = out;
        ushort4 phi, plo;
#pragma unroll
        for (int r = 0; r < 4; r++) {
            float v = (&out.x)[r];
            u16 hi = f2bf(v);
            u16 lo = f2bf(v - bf2f(hi));
            (&phi.x)[r] = hi; (&plo.x)[r] = lo;
        }
        *(ushort4*)(shi + nd * LDP + ch) = phi;
        *(ushort4*)(slo + nd * LDP + ch) = plo;
    }
    __syncthreads();
    // A fragments from LDS
    int arow = ml * LDP + kb;
    bf16x8 ah0 = *(const bf16x8*)(shi + arow);
    bf16x8 ah1 = *(const bf16x8*)(shi + arow + 32);
    bf16x8 al0 = *(const bf16x8*)(slo + arow);
    bf16x8 al1 = *(const bf16x8*)(slo + arow + 32);
    int row = node0 + (lane >> 4) * 4;
#pragma unroll
    for (int c = 0; c < 4; c++) {
        f32x4 acc = {0.f, 0.f, 0.f, 0.f};
        acc = __builtin_amdgcn_mfma_f32_16x16x32_bf16(al0, bh[c][0], acc, 0, 0, 0);
        acc = __builtin_amdgcn_mfma_f32_16x16x32_bf16(al1, bh[c][1], acc, 0, 0, 0);
        acc = __builtin_amdgcn_mfma_f32_16x16x32_bf16(ah0, bl[c][0], acc, 0, 0, 0);
        acc = __builtin_amdgcn_mfma_f32_16x16x32_bf16(ah1, bl[c][1], acc, 0, 0, 0);
        acc = __builtin_amdgcn_mfma_f32_16x16x32_bf16(ah0, bh[c][0], acc, 0, 0, 0);
        acc = __builtin_amdgcn_mfma_f32_16x16x32_bf16(ah1, bh[c][1], acc, 0, 0, 0);
        int colj = (wv * 4 + c) * 16 + ml;
#pragma unroll
        for (int r = 0; r < 4; r++) xlxr[(size_t)(row + r) * 256 + colj] = f2bf(acc[r]);
    }
}

// ---- GATv2 attention v3: 16-lane subset per dst (4 dsts/wave), serial online softmax ----
// lane = 16*gsub + q; lane handles channels 8q..8q+7; q<8 -> head0, q>=8 -> head1
__global__ __launch_bounds__(256) void k_edge(const uint4* __restrict__ xw4, const int* __restrict__ rp,
                                              const int* __restrict__ col, const float* __restrict__ attL,
                                              const float* __restrict__ cbL, float* __restrict__ g,
                                              float* __restrict__ bns) {
    __shared__ float ls[64], lq[64];
    int t = threadIdx.x;
    if (t < 64) { ls[t] = 0.f; lq[t] = 0.f; }
    __syncthreads();
    int lane = t & 63;
    int q = lane & 15;
    int gsub = lane >> 4;
    int slot = (blockIdx.x * 4 + (t >> 6)) * 4 + gsub;
    int nslot = gridDim.x * 16;
    float atv[8];
#pragma unroll
    for (int i = 0; i < 8; i++) atv[i] = attL[8 * q + i];
    float cbv[8];
#pragma unroll
    for (int i = 0; i < 8; i++) cbv[i] = 0.f;
    if (q < 8) {
#pragma unroll
        for (int i = 0; i < 8; i++) cbv[i] = cbL[8 * q + i];
    }
    float sacc[8], qacc[8];
#pragma unroll
    for (int i = 0; i < 8; i++) { sacc[i] = 0.f; qacc[i] = 0.f; }
    for (int d = slot; d < NN; d += nslot) {
        float xr[8];
        { uint4 w = xw4[(size_t)d * 32 + 16 + q]; unpack8(w, xr); }
        int beg = rp[d], end = rp[d + 1];
        float m = -1e30f, lsum = 0.f;
        float acc[8];
#pragma unroll
        for (int i = 0; i < 8; i++) acc[i] = 0.f;
        int s0 = col[beg];  // deg >= 1 guaranteed (self-loop)
        uint4 xlw = xw4[(size_t)s0 * 32 + q];
        for (int idx = beg; idx < end; idx++) {
            uint4 curw = xlw;
            if (idx + 1 < end) {
                int s2 = col[idx + 1];
                xlw = xw4[(size_t)s2 * 32 + q];
            }
            float xl[8]; unpack8(curw, xl);
            float p = 0.f;
#pragma unroll
            for (int i = 0; i < 8; i++) {
                float u = xl[i] + xr[i];
                float lr = u > 0.f ? u : 0.2f * u;
                p += lr * atv[i];
            }
            p += __shfl_xor(p, 1); p += __shfl_xor(p, 2); p += __shfl_xor(p, 4);
            float mn = fmaxf(m, p);
            float sc = __expf(m - mn);
            float pw = __expf(p - mn);
            lsum = lsum * sc + pw;
#pragma unroll
            for (int i = 0; i < 8; i++) acc[i] = acc[i] * sc + pw * xl[i];
            m = mn;
        }
        float inv = 1.0f / (lsum + 1e-16f);
#pragma unroll
        for (int i = 0; i < 8; i++) {
            float v = acc[i] * inv;
            acc[i] = 0.5f * (v + __shfl_xor(v, 8));  // head average
        }
        if (q < 8) {
            float4 w0, w1;
#pragma unroll
            for (int i = 0; i < 8; i++) {
                float c = acc[i] + cbv[i];
                sacc[i] += c; qacc[i] += c * c;
                if (i < 4) (&w0.x)[i] = c; else (&w1.x)[i - 4] = c;
            }
            *(float4*)(g + (size_t)d * 64 + 8 * q) = w0;
            *(float4*)(g + (size_t)d * 64 + 8 * q + 4) = w1;
        }
    }
    if (q < 8) {
#pragma unroll
        for (int i = 0; i < 8; i++) {
            atomicAdd(&ls[8 * q + i], sacc[i]);
            atomicAdd(&lq[8 * q + i], qacc[i]);
        }
    }
    __syncthreads();
    if (t < 64) atomicAdd(&bns[t], ls[t]);
    else if (t < 128) atomicAdd(&bns[t], lq[t - 64]);
}

// ---- final BN+ELU+residual (layer 12), h only ----
__global__ void k_bnfinal(const float* __restrict__ g, const float* __restrict__ bns,
                          const float* __restrict__ gamma, const float* __restrict__ beta, float* h) {
    int t = blockIdx.x * blockDim.x + threadIdx.x;
    if (t >= NN * 16) return;
    int c4 = (t & 15) * 4;
    float4 gg = *(const float4*)(g + (size_t)t * 4);
    float4 out;
#pragma unroll
    for (int r = 0; r < 4; r++) {
        int c = c4 + r;
        float mean = bns[c] * (1.0f / NN);
        float var = bns[64 + c] * (1.0f / NN) - mean * mean;
        var = fmaxf(var, 0.f);
        float rstd = rsqrtf(var + EPS_BN);
        float v = ((&gg.x)[r] - mean) * rstd * gamma[c] + beta[c];
        (&out.x)[r] = v > 0.f ? v : (__expf(v) - 1.f);
    }
    float4 hh = *(const float4*)(h + (size_t)t * 4);
    out.x += hh.x; out.y += hh.y; out.z += hh.z; out.w += hh.w;
    *(float4*)(h + (size_t)t * 4) = out;
}

// ---- output head ----
__global__ void k_head(const float* __restrict__ h, const float* __restrict__ W1, const float* __restrict__ b1,
                       const float* __restrict__ W2, const float* __restrict__ b2, float* __restrict__ out) {
    int t = blockIdx.x * blockDim.x + threadIdx.x;
    int node = t >> 5;
    int j = t & 31;
    if (node >= NN) return;
    float acc = b1[j];
    const float* hr = h + (size_t)node * 64;
#pragma unroll
    for (int k = 0; k < 64; k++) acc += hr[k] * W1[k * 32 + j];
    float e = acc > 0.f ? acc : (__expf(acc) - 1.f);
    float z = e * W2[j];
    z += __shfl_xor(z, 1); z += __shfl_xor(z, 2); z += __shfl_xor(z, 4);
    z += __shfl_xor(z, 8); z += __shfl_xor(z, 16);
    if (j == 0) {
        float y = z + b2[0];
        out[node] = 1.0f / (1.0f + __expf(-y));
    }
}

extern "C" void kernel_launch(void* const* d_in, const int* in_sizes, int n_in,
                              void* d_out, int out_size, void* d_ws, size_t ws_size,
                              hipStream_t stream) {
    const float* x = (const float*)d_in[0];
    const int* ei = (const int*)d_in[1];
    const float* inW = (const float*)d_in[2];
    const float* inb = (const float*)d_in[3];
    const float* ing = (const float*)d_in[4];
    const float* inbeta = (const float*)d_in[5];
    const float* Wl = (const float*)d_in[6];
    const float* Wr = (const float*)d_in[7];
    const float* att = (const float*)d_in[8];
    const float* cb = (const float*)d_in[9];
    const float* bng = (const float*)d_in[10];
    const float* bnb = (const float*)d_in[11];
    const float* W1 = (const float*)d_in[12];
    const float* b1 = (const float*)d_in[13];
    const float* W2 = (const float*)d_in[14];
    const float* b2 = (const float*)d_in[15];
    float* out = (float*)d_out;

    char* ws = (char*)d_ws;
    size_t off = 0;
    auto alloc = [&](size_t bytes) -> char* {
        char* p = ws + off;
        off = (off + bytes + 255) & ~(size_t)255;
        return p;
    };
    float* h    = (float*)alloc((size_t)NN * 64 * 4);
    float* g    = (float*)alloc((size_t)NN * 64 * 4);
    u16* xlxr   = (u16*)alloc((size_t)NN * 256 * 2);
    u16* WThi   = (u16*)alloc((size_t)NLAYERS * 256 * 64 * 2);
    u16* WTlo   = (u16*)alloc((size_t)NLAYERS * 256 * 64 * 2);
    int* deg    = (int*)alloc((size_t)NN * 4);
    int* rp     = (int*)alloc((size_t)(NN + 1) * 4);
    int* cur    = (int*)alloc((size_t)NN * 4);
    int* colv   = (int*)alloc((size_t)NET * 4);
    int* stmp   = (int*)alloc((size_t)NN * 4);
    int* part   = (int*)alloc(256 * 4);
    float* bns  = (float*)alloc((size_t)(NLAYERS + 1) * 128 * 4);

    k_zero_i<<<(NN + 255) / 256, 256, 0, stream>>>(deg, NN);
    k_zero_f<<<((NLAYERS + 1) * 128 + 255) / 256, 256, 0, stream>>>(bns, (NLAYERS + 1) * 128);

    k_wt<<<(NLAYERS * 256 * HIDC + 255) / 256, 256, 0, stream>>>(Wl, Wr, WThi, WTlo);
    k_count<<<(NE + 255) / 256, 256, 0, stream>>>(ei, deg);
    k_scan1<<<196, 256, 0, stream>>>(deg, stmp, part);
    k_scan2<<<1, 256, 0, stream>>>(part);
    k_scan3<<<196, 256, 0, stream>>>(deg, stmp, part, rp, cur);
    k_scatter<<<(NET + 255) / 256, 256, 0, stream>>>(ei, cur, colv);

    k_inproj<<<512, 256, 0, stream>>>(x, inW, inb, g, bns);

    for (int i = 0; i < NLAYERS; i++) {
        const float* gamma = (i == 0) ? ing : bng + (size_t)(i - 1) * 64;
        const float* beta  = (i == 0) ? inbeta : bnb + (size_t)(i - 1) * 64;
        k_gemmbn<<<3125, 256, 0, stream>>>(g, bns + (size_t)i * 128, gamma, beta, h, (i > 0) ? 1 : 0,
                                           WThi + (size_t)i * 16384, WTlo + (size_t)i * 16384, xlxr);
        k_edge<<<1563, 256, 0, stream>>>((const uint4*)xlxr, rp, colv,
                                         att + (size_t)i * 128, cb + (size_t)i * 64,
                                         g, bns + (size_t)(i + 1) * 128);
    }
    k_bnfinal<<<3125, 256, 0, stream>>>(g, bns + (size_t)NLAYERS * 128,
                                        bng + (size_t)(NLAYERS - 1) * 64, bnb + (size_t)(NLAYERS - 1) * 64, h);
    k_head<<<6250, 256, 0, stream>>>(h, W1, b1, W2, b2, out);
}